// Round 1
// baseline (466.040 us; speedup 1.0000x reference)
//
#include <hip/hip_runtime.h>
#include <hip/hip_bf16.h>

#define NN 100000
#define DD 128
#define KNN 20

typedef unsigned short u16;
typedef __attribute__((ext_vector_type(8))) __bf16 bf16x8;
typedef __attribute__((ext_vector_type(4))) float f32x4;
typedef __attribute__((ext_vector_type(4))) unsigned short u16x4;
typedef __attribute__((ext_vector_type(8))) unsigned short u16x8;

__device__ __forceinline__ float b2f(u16 b) {
  unsigned int u = ((unsigned int)b) << 16;
  float f;
  __builtin_memcpy(&f, &u, 4);
  return f;
}
__device__ __forceinline__ u16 f2b(float f) {
  unsigned int u;
  __builtin_memcpy(&u, &f, 4);
  u += 0x7fffu + ((u >> 16) & 1u);
  return (u16)(u >> 16);
}

// ---------------- weight staging: f32 W -> bf16 frag-linear W^T blocks ----------------
// Frag idx = kc*32 + ct*4 + ksl (ks = kc*4+ksl); dst[(idx*64+lane)*8 + j]
//   = bf16( W[(ks*32 + quad*8 + j)*wstride + colbase + ct*16 + l16] )
// Used as MFMA *A*-operand: A[m=l16 -> wcol][k=quad*8+j]; compute side reads one
// contiguous coalesced 1KB b128 per frag.
__device__ __forceinline__ void stage_frag(const float* __restrict__ W, int wstride,
                                           int colbase, u16* __restrict__ dst, int f) {
  int lane = f & 63;
  int t2 = f >> 6;
  int ksl = t2 & 3;
  int ct = (t2 >> 2) & 7;
  int kc = t2 >> 5;
  int ks = kc * 4 + ksl;
  int quad = lane >> 4, l16 = lane & 15;
  const float* src = W + (size_t)(ks * 32 + quad * 8) * wstride + colbase + ct * 16 + l16;
  u16x8 o;
#pragma unroll
  for (int j = 0; j < 8; j++) o[j] = f2b(src[(size_t)j * wstride]);
  *(u16x8*)(dst + (size_t)f * 8) = o;
}

// WTf (u16 offsets): Wq@0, Wk@16384, Wv@32768, Wo@49152, W1a@65536, W1b@81920, W2@98304
__global__ __launch_bounds__(256) void stage_weights_kernel(
    const float* __restrict__ Wq, const float* __restrict__ Wk, const float* __restrict__ Wv,
    const float* __restrict__ Wo, const float* __restrict__ W1, const float* __restrict__ W2,
    const float* __restrict__ g1, const float* __restrict__ b1,
    const float* __restrict__ m1, const float* __restrict__ v1,
    const float* __restrict__ g2, const float* __restrict__ b2,
    const float* __restrict__ m2, const float* __restrict__ v2,
    const float* __restrict__ bo,
    u16* __restrict__ WTf,
    float* __restrict__ sc1, float* __restrict__ bb1,
    float* __restrict__ sc2, float* __restrict__ bb2, float* __restrict__ bof)
{
  int t = blockIdx.x * 256 + threadIdx.x;
  if (t < 2048)       stage_frag(Wq, 128, 0,   WTf + 0,     t);
  else if (t < 4096)  stage_frag(Wk, 128, 0,   WTf + 16384, t - 2048);
  else if (t < 6144)  stage_frag(Wv, 128, 0,   WTf + 32768, t - 4096);
  else if (t < 8192)  stage_frag(Wo, 128, 0,   WTf + 49152, t - 6144);
  else if (t < 10240) stage_frag(W1, 256, 0,   WTf + 65536, t - 8192);
  else if (t < 12288) stage_frag(W1, 256, 128, WTf + 81920, t - 10240);
  else if (t < 16384) stage_frag(W2, 128, 0,   WTf + 98304, t - 12288);
  else if (t < 16512) {
    int c = t - 16384;
    float s1 = g1[c] * rsqrtf(v1[c] + 1e-5f);
    sc1[c] = s1; bb1[c] = b1[c] - m1[c] * s1;
    float s2 = g2[c] * rsqrtf(v2[c] + 1e-5f);
    sc2[c] = s2; bb2[c] = b2[c] - m2[c] * s2;
    bof[c] = bo[c];
  }
}

// ---------------- kernel A: fused bn1 + QKV, 16 rows/wave ----------------
// Operand-swapped MFMA: D = Wfrag(A) x actfrag(B) -> lane l16 = node row,
// quad*4+r = channel -> u16x4 vector stores. q->qb[N,128]; k,v interleaved ->kvb[N,256].
__global__ __launch_bounds__(256) void qkv_kernel(
    const float* __restrict__ f, const u16* __restrict__ WTf,
    const float* __restrict__ sc1, const float* __restrict__ bb1,
    u16* __restrict__ qb, u16* __restrict__ kvb)
{
  const int tid = threadIdx.x;
  const int wave = tid >> 6, lane = tid & 63, quad = lane >> 4, l16 = lane & 15;
  const int rowbase = blockIdx.x * 64 + wave * 16;
  int arow = rowbase + l16;
  if (arow >= NN) arow = NN - 1;

  // act frags (B-op): lane = row l16, k = ks*32+quad*8+j ; bn1 folded in regs
  bf16x8 af[4];
#pragma unroll
  for (int ks = 0; ks < 4; ks++) {
    int ch = ks * 32 + quad * 8;
    f32x4 s0 = *(const f32x4*)(sc1 + ch), s1 = *(const f32x4*)(sc1 + ch + 4);
    f32x4 c0 = *(const f32x4*)(bb1 + ch), c1 = *(const f32x4*)(bb1 + ch + 4);
    const float* fp = f + (size_t)arow * DD + ch;
    f32x4 x0 = *(const f32x4*)(fp), x1 = *(const f32x4*)(fp + 4);
    u16x8 hv;
#pragma unroll
    for (int j = 0; j < 4; j++) {
      hv[j]     = f2b(x0[j] * s0[j] + c0[j]);
      hv[j + 4] = f2b(x1[j] * s1[j] + c1[j]);
    }
    af[ks] = __builtin_bit_cast(bf16x8, hv);
  }

  const int srow = rowbase + l16;
  u16x4 ks16[8];  // k results held for interleaved kv store
#pragma unroll
  for (int m = 0; m < 3; m++) {
    f32x4 acc[8];
#pragma unroll
    for (int ct = 0; ct < 8; ct++) acc[ct] = (f32x4){0.f, 0.f, 0.f, 0.f};
#pragma unroll
    for (int ct = 0; ct < 8; ct++)
#pragma unroll
      for (int ks = 0; ks < 4; ks++) {
        bf16x8 wf = *(const bf16x8*)(WTf + (size_t)m * 16384 + ((ct * 4 + ks) * 64 + lane) * 8);
        acc[ct] = __builtin_amdgcn_mfma_f32_16x16x32_bf16(wf, af[ks], acc[ct], 0, 0, 0);
      }
#pragma unroll
    for (int ct = 0; ct < 8; ct++) {
      int ch0 = ct * 16 + quad * 4;
      if (m == 0) {
        if (srow < NN) {
          u16x4 o;
#pragma unroll
          for (int r = 0; r < 4; r++) o[r] = f2b(acc[ct][r]);
          *(u16x4*)(qb + (size_t)srow * DD + ch0) = o;
        }
      } else if (m == 1) {
        u16x4 o;
#pragma unroll
        for (int r = 0; r < 4; r++) o[r] = f2b(acc[ct][r]);
        ks16[ct] = o;
      } else {
        if (srow < NN) {
          u16x8 o;
#pragma unroll
          for (int r = 0; r < 4; r++) {
            o[2 * r] = ks16[ct][r];
            o[2 * r + 1] = f2b(acc[ct][r]);
          }
          *(u16x8*)(kvb + (size_t)srow * 256 + ch0 * 2) = o;
        }
      }
    }
  }
}

// ---------------- attention: 32 lanes/node, 4 ch/lane, interleaved kv ----------------
// UNCHANGED this round: control experiment for the L3-footprint theory.
__global__ __launch_bounds__(256) void attn_kernel(
    const u16* __restrict__ q, const u16* __restrict__ kv,
    const int* __restrict__ src, u16* __restrict__ attnb)
{
  const int node = blockIdx.x * 8 + (threadIdx.x >> 5);
  const int sub = threadIdx.x & 31;
  const int c0 = sub * 4;
  const size_t qbase = (size_t)node * DD + c0;

  u16x4 qr = *(const u16x4*)(q + qbase);
  const float qv0 = b2f(qr[0]), qv1 = b2f(qr[1]), qv2 = b2f(qr[2]), qv3 = b2f(qr[3]);

  int sv[KNN];
  const int* sp = src + (size_t)node * KNN;
#pragma unroll
  for (int j = 0; j < KNN; j++) sv[j] = sp[j];

  float a0 = 0.f, a1 = 0.f, a2 = 0.f, a3 = 0.f, z = 0.f;
  const float inv_sqrt_hd = 0.17677669529663687f;  // 1/sqrt(32)
#pragma unroll 10
  for (int j = 0; j < KNN; j++) {
    u16x8 kvr = *(const u16x8*)(kv + (size_t)sv[j] * 256 + c0 * 2);
    float p = b2f(kvr[0]) * qv0 + b2f(kvr[2]) * qv1 + b2f(kvr[4]) * qv2 + b2f(kvr[6]) * qv3;
    p += __shfl_xor(p, 1);
    p += __shfl_xor(p, 2);
    p += __shfl_xor(p, 4);
    float sc = __expf(fminf(fmaxf(p * inv_sqrt_hd, -5.f), 5.f));
    z += sc;
    a0 += sc * b2f(kvr[1]);
    a1 += sc * b2f(kvr[3]);
    a2 += sc * b2f(kvr[5]);
    a3 += sc * b2f(kvr[7]);
  }
  float inv = 1.f / (z + 1e-6f);
  u16x4 o;
  o[0] = f2b(a0 * inv); o[1] = f2b(a1 * inv);
  o[2] = f2b(a2 * inv); o[3] = f2b(a3 * inv);
  *(u16x4*)(attnb + qbase) = o;
}

// ---------------- fused kernel B: out = node + silu(bn2(node)@W1)@W2,
//                  node = attn@Wo + bo + f  (kept entirely in registers) ----------------
// 16 rows/wave. node (f32) and h2 (bf16) intermediates never touch global memory:
// saves 154 MB traffic/iter AND shrinks the iteration footprint below the 256 MB L3
// so kvb can stay Infinity-Cache-resident for attn.
// h2 relayout C/D->B-frag via the same wave-private LDS tile trick as the silu path
// (per-wave DS ops are in-order; no barriers needed).
__global__ __launch_bounds__(256) void womlp_kernel(
    const u16* __restrict__ attnb, const float* __restrict__ f, const u16* __restrict__ WTf,
    const float* __restrict__ bof, const float* __restrict__ sc2, const float* __restrict__ bb2,
    float* __restrict__ out)
{
  __shared__ u16 T[8704];  // 4 waves x 2176 u16 (16 rows x 136; 272B row stride, 16B aligned)
  const int tid = threadIdx.x;
  const int wave = tid >> 6, lane = tid & 63, quad = lane >> 4, l16 = lane & 15;
  const int rowbase = blockIdx.x * 64 + wave * 16;
  u16* tile = T + wave * 2176;
  int arow = rowbase + l16;
  if (arow >= NN) arow = NN - 1;

  // ---- attn @ Wo ----
  bf16x8 af[4];
  const u16* ap = attnb + (size_t)arow * DD + quad * 8;
#pragma unroll
  for (int ks = 0; ks < 4; ks++) af[ks] = *(const bf16x8*)(ap + ks * 32);

  f32x4 nv[8];
#pragma unroll
  for (int ct = 0; ct < 8; ct++) nv[ct] = (f32x4){0.f, 0.f, 0.f, 0.f};
#pragma unroll
  for (int ct = 0; ct < 8; ct++)
#pragma unroll
    for (int ks = 0; ks < 4; ks++) {
      bf16x8 wf = *(const bf16x8*)(WTf + 49152 + ((ct * 4 + ks) * 64 + lane) * 8);
      nv[ct] = __builtin_amdgcn_mfma_f32_16x16x32_bf16(wf, af[ks], nv[ct], 0, 0, 0);
    }

  // node = nv + bo + f (held in nv registers); h2 = bn2(node) -> tile -> B-frags
#pragma unroll
  for (int ct = 0; ct < 8; ct++) {
    int ch0 = ct * 16 + quad * 4;
    f32x4 bo4 = *(const f32x4*)(bof + ch0);
    f32x4 s4  = *(const f32x4*)(sc2 + ch0);
    f32x4 b4  = *(const f32x4*)(bb2 + ch0);
    f32x4 f4  = *(const f32x4*)(f + (size_t)arow * DD + ch0);
    nv[ct] = nv[ct] + bo4 + f4;
    u16x4 h4;
#pragma unroll
    for (int r = 0; r < 4; r++) h4[r] = f2b(nv[ct][r] * s4[r] + b4[r]);
    *(u16x4*)(tile + l16 * 136 + ch0) = h4;
  }
  bf16x8 hf[4];
#pragma unroll
  for (int ksl = 0; ksl < 4; ksl++)
    hf[ksl] = *(const bf16x8*)(tile + l16 * 136 + ksl * 32 + quad * 8);

  // ---- MLP: silu(h2@W1)@W2 ----
  f32x4 acc3[8];
#pragma unroll
  for (int ct = 0; ct < 8; ct++) acc3[ct] = (f32x4){0.f, 0.f, 0.f, 0.f};

#pragma unroll
  for (int m = 0; m < 2; m++) {
    f32x4 acc2[8];
#pragma unroll
    for (int ct = 0; ct < 8; ct++) acc2[ct] = (f32x4){0.f, 0.f, 0.f, 0.f};
#pragma unroll
    for (int ct = 0; ct < 8; ct++)
#pragma unroll
      for (int ks = 0; ks < 4; ks++) {
        bf16x8 wf = *(const bf16x8*)(WTf + 65536 + m * 16384 + ((ct * 4 + ks) * 64 + lane) * 8);
        acc2[ct] = __builtin_amdgcn_mfma_f32_16x16x32_bf16(wf, hf[ks], acc2[ct], 0, 0, 0);
      }
    // silu -> tile (C/D layout) -> read back as B-frags
#pragma unroll
    for (int ct = 0; ct < 8; ct++) {
      int ch0 = ct * 16 + quad * 4;
      u16x4 i4;
#pragma unroll
      for (int r = 0; r < 4; r++) {
        float x = acc2[ct][r];
        i4[r] = f2b(x / (1.f + __expf(-x)));
      }
      *(u16x4*)(tile + l16 * 136 + ch0) = i4;
    }
    bf16x8 iff[4];
#pragma unroll
    for (int ksl = 0; ksl < 4; ksl++)
      iff[ksl] = *(const bf16x8*)(tile + l16 * 136 + ksl * 32 + quad * 8);
    // W2 partial: global k-slice = m*4+ksl; W2 frag idx = m*32 + ct*4 + ksl
#pragma unroll
    for (int ct = 0; ct < 8; ct++)
#pragma unroll
      for (int ksl = 0; ksl < 4; ksl++) {
        bf16x8 wf = *(const bf16x8*)(WTf + 98304 + ((m * 32 + ct * 4 + ksl) * 64 + lane) * 8);
        acc3[ct] = __builtin_amdgcn_mfma_f32_16x16x32_bf16(wf, iff[ksl], acc3[ct], 0, 0, 0);
      }
  }

  // ---- out = node + mlp ----
  const int srow = rowbase + l16;
  if (srow < NN) {
#pragma unroll
    for (int ct = 0; ct < 8; ct++) {
      int ch0 = ct * 16 + quad * 4;
      *(f32x4*)(out + (size_t)srow * DD + ch0) = acc3[ct] + nv[ct];
    }
  }
}

extern "C" void kernel_launch(void* const* d_in, const int* in_sizes, int n_in,
                              void* d_out, int out_size, void* d_ws, size_t ws_size,
                              hipStream_t stream) {
  const float* f  = (const float*)d_in[0];
  const int* src  = (const int*)d_in[1];
  // d_in[2] = dst (structure known: repeat(arange(N),20)) -- unused
  const float* g1 = (const float*)d_in[3];
  const float* b1 = (const float*)d_in[4];
  const float* m1 = (const float*)d_in[5];
  const float* v1 = (const float*)d_in[6];
  const float* Wq = (const float*)d_in[7];
  const float* Wk = (const float*)d_in[8];
  const float* Wv = (const float*)d_in[9];
  const float* Wo = (const float*)d_in[10];
  const float* bo = (const float*)d_in[11];
  const float* g2 = (const float*)d_in[12];
  const float* b2 = (const float*)d_in[13];
  const float* m2 = (const float*)d_in[14];
  const float* v2 = (const float*)d_in[15];
  const float* W1 = (const float*)d_in[16];
  const float* W2 = (const float*)d_in[17];
  float* out = (float*)d_out;   // f32 output

  char* ws = (char*)d_ws;
  u16*  WTf = (u16*)(ws + 0);                    // 262144 B
  float* sc1 = (float*)(ws + 262144);
  float* bb1 = (float*)(ws + 262656);
  float* sc2 = (float*)(ws + 263168);
  float* bb2 = (float*)(ws + 263680);
  float* bof = (float*)(ws + 264192);
  // buffer plan (node/h2 intermediates eliminated by wo+mlp fusion):
  //   qb    @ 1MB   (25.6 MB)
  //   kvb   @ 27MB  (51.2 MB)
  //   attnb @ 79MB  (25.6 MB)
  // live footprint/iter: f 51.2 + qb 25.6 + kvb 51.2 + attnb 25.6 + out 51.2 ~ 205 MB < 256 MB L3
  u16*   qb    = (u16*)(ws + (1u << 20));
  u16*   kvb   = (u16*)(ws + 27262976u);
  u16*   attnb = (u16*)(ws + 80740352u);

  stage_weights_kernel<<<65, 256, 0, stream>>>(
      Wq, Wk, Wv, Wo, W1, W2, g1, b1, m1, v1, g2, b2, m2, v2, bo,
      WTf, sc1, bb1, sc2, bb2, bof);

  const int ggrid = (NN + 63) / 64;  // 1563
  qkv_kernel<<<ggrid, 256, 0, stream>>>(f, WTf, sc1, bb1, qb, kvb);
  attn_kernel<<<NN / 8, 256, 0, stream>>>(qb, kvb, src, attnb);
  womlp_kernel<<<ggrid, 256, 0, stream>>>(attnb, f, WTf, bof, sc2, bb2, out);
}

// Round 2
// 381.329 us; speedup vs baseline: 1.2221x; 1.2221x over previous
//
#include <hip/hip_runtime.h>
#include <hip/hip_bf16.h>

#define NN 100000
#define DD 128
#define KNN 20

typedef unsigned short u16;
typedef __attribute__((ext_vector_type(8))) __bf16 bf16x8;
typedef __attribute__((ext_vector_type(4))) float f32x4;
typedef __attribute__((ext_vector_type(4))) unsigned short u16x4;
typedef __attribute__((ext_vector_type(8))) unsigned short u16x8;

__device__ __forceinline__ float b2f(u16 b) {
  unsigned int u = ((unsigned int)b) << 16;
  float f;
  __builtin_memcpy(&f, &u, 4);
  return f;
}
__device__ __forceinline__ u16 f2b(float f) {
  unsigned int u;
  __builtin_memcpy(&u, &f, 4);
  u += 0x7fffu + ((u >> 16) & 1u);
  return (u16)(u >> 16);
}

// ---------------- weight staging: f32 W -> bf16 frag-linear W^T blocks ----------------
// Frag idx = kc*32 + ct*4 + ksl (ks = kc*4+ksl); dst[(idx*64+lane)*8 + j]
//   = bf16( W[(ks*32 + quad*8 + j)*wstride + colbase + ct*16 + l16] )
// Used as MFMA *A*-operand: A[m=l16 -> wcol][k=quad*8+j].
__device__ __forceinline__ void stage_frag(const float* __restrict__ W, int wstride,
                                           int colbase, u16* __restrict__ dst, int f) {
  int lane = f & 63;
  int t2 = f >> 6;
  int ksl = t2 & 3;
  int ct = (t2 >> 2) & 7;
  int kc = t2 >> 5;
  int ks = kc * 4 + ksl;
  int quad = lane >> 4, l16 = lane & 15;
  const float* src = W + (size_t)(ks * 32 + quad * 8) * wstride + colbase + ct * 16 + l16;
  u16x8 o;
#pragma unroll
  for (int j = 0; j < 8; j++) o[j] = f2b(src[(size_t)j * wstride]);
  *(u16x8*)(dst + (size_t)f * 8) = o;
}

// WTf (u16 offsets): Wq@0, Wk@16384, Wv@32768, Wo@49152, W1a@65536, W1b@81920, W2@98304
__global__ __launch_bounds__(256) void stage_weights_kernel(
    const float* __restrict__ Wq, const float* __restrict__ Wk, const float* __restrict__ Wv,
    const float* __restrict__ Wo, const float* __restrict__ W1, const float* __restrict__ W2,
    const float* __restrict__ g1, const float* __restrict__ b1,
    const float* __restrict__ m1, const float* __restrict__ v1,
    const float* __restrict__ g2, const float* __restrict__ b2,
    const float* __restrict__ m2, const float* __restrict__ v2,
    const float* __restrict__ bo,
    u16* __restrict__ WTf,
    float* __restrict__ sc1, float* __restrict__ bb1,
    float* __restrict__ sc2, float* __restrict__ bb2, float* __restrict__ bof)
{
  int t = blockIdx.x * 256 + threadIdx.x;
  if (t < 2048)       stage_frag(Wq, 128, 0,   WTf + 0,     t);
  else if (t < 4096)  stage_frag(Wk, 128, 0,   WTf + 16384, t - 2048);
  else if (t < 6144)  stage_frag(Wv, 128, 0,   WTf + 32768, t - 4096);
  else if (t < 8192)  stage_frag(Wo, 128, 0,   WTf + 49152, t - 6144);
  else if (t < 10240) stage_frag(W1, 256, 0,   WTf + 65536, t - 8192);
  else if (t < 12288) stage_frag(W1, 256, 128, WTf + 81920, t - 10240);
  else if (t < 16384) stage_frag(W2, 128, 0,   WTf + 98304, t - 12288);
  else if (t < 16512) {
    int c = t - 16384;
    float s1 = g1[c] * rsqrtf(v1[c] + 1e-5f);
    sc1[c] = s1; bb1[c] = b1[c] - m1[c] * s1;
    float s2 = g2[c] * rsqrtf(v2[c] + 1e-5f);
    sc2[c] = s2; bb2[c] = b2[c] - m2[c] * s2;
    bof[c] = bo[c];
  }
}

// Block-level weight stage: copy one 32KB frag-linear matrix (16384 u16) into LDS.
// 256 threads x 8 x 16B, fully coalesced. Callers barrier around it.
__device__ __forceinline__ void stage_lds(u16* __restrict__ LW,
                                          const u16* __restrict__ src, int tid) {
#pragma unroll
  for (int k2 = 0; k2 < 8; k2++) {
    size_t o = (size_t)(k2 * 256 + tid) * 8;
    *(u16x8*)(LW + o) = *(const u16x8*)(src + o);
  }
}

// ---------------- kernel A: fused bn1 + QKV, 16 rows/wave ----------------
// Weight frags now staged per-BLOCK into LDS (4x cut in L2 weight stream) and
// consumed via ds_read_b128; MFMA structure and store layout unchanged.
__global__ __launch_bounds__(256) void qkv_kernel(
    const float* __restrict__ f, const u16* __restrict__ WTf,
    const float* __restrict__ sc1, const float* __restrict__ bb1,
    u16* __restrict__ qb, u16* __restrict__ kvb)
{
  __shared__ u16 LW[16384];  // 32 KB: one staged weight matrix
  const int tid = threadIdx.x;
  const int wave = tid >> 6, lane = tid & 63, quad = lane >> 4, l16 = lane & 15;
  const int rowbase = blockIdx.x * 64 + wave * 16;
  int arow = rowbase + l16;
  if (arow >= NN) arow = NN - 1;

  // act frags (B-op): lane = row l16, k = ks*32+quad*8+j ; bn1 folded in regs
  bf16x8 af[4];
#pragma unroll
  for (int ks = 0; ks < 4; ks++) {
    int ch = ks * 32 + quad * 8;
    f32x4 s0 = *(const f32x4*)(sc1 + ch), s1 = *(const f32x4*)(sc1 + ch + 4);
    f32x4 c0 = *(const f32x4*)(bb1 + ch), c1 = *(const f32x4*)(bb1 + ch + 4);
    const float* fp = f + (size_t)arow * DD + ch;
    f32x4 x0 = *(const f32x4*)(fp), x1 = *(const f32x4*)(fp + 4);
    u16x8 hv;
#pragma unroll
    for (int j = 0; j < 4; j++) {
      hv[j]     = f2b(x0[j] * s0[j] + c0[j]);
      hv[j + 4] = f2b(x1[j] * s1[j] + c1[j]);
    }
    af[ks] = __builtin_bit_cast(bf16x8, hv);
  }

  const int srow = rowbase + l16;
  u16x4 ks16[8];  // k results held for interleaved kv store
#pragma unroll
  for (int m = 0; m < 3; m++) {
    __syncthreads();                       // previous phase's LW readers done
    stage_lds(LW, WTf + m * 16384, tid);
    __syncthreads();                       // staged data visible to all waves
    f32x4 acc[8];
#pragma unroll
    for (int ct = 0; ct < 8; ct++) acc[ct] = (f32x4){0.f, 0.f, 0.f, 0.f};
#pragma unroll
    for (int ct = 0; ct < 8; ct++)
#pragma unroll
      for (int ks = 0; ks < 4; ks++) {
        bf16x8 wf = *(const bf16x8*)(LW + ((ct * 4 + ks) * 64 + lane) * 8);
        acc[ct] = __builtin_amdgcn_mfma_f32_16x16x32_bf16(wf, af[ks], acc[ct], 0, 0, 0);
      }
#pragma unroll
    for (int ct = 0; ct < 8; ct++) {
      int ch0 = ct * 16 + quad * 4;
      if (m == 0) {
        if (srow < NN) {
          u16x4 o;
#pragma unroll
          for (int r = 0; r < 4; r++) o[r] = f2b(acc[ct][r]);
          *(u16x4*)(qb + (size_t)srow * DD + ch0) = o;
        }
      } else if (m == 1) {
        u16x4 o;
#pragma unroll
        for (int r = 0; r < 4; r++) o[r] = f2b(acc[ct][r]);
        ks16[ct] = o;
      } else {
        if (srow < NN) {
          u16x8 o;
#pragma unroll
          for (int r = 0; r < 4; r++) {
            o[2 * r] = ks16[ct][r];
            o[2 * r + 1] = f2b(acc[ct][r]);
          }
          *(u16x8*)(kvb + (size_t)srow * 256 + ch0 * 2) = o;
        }
      }
    }
  }
}

// ---------------- attention: 32 lanes/node, 4 ch/lane, interleaved kv ----------------
// UNCHANGED.
__global__ __launch_bounds__(256) void attn_kernel(
    const u16* __restrict__ q, const u16* __restrict__ kv,
    const int* __restrict__ src, u16* __restrict__ attnb)
{
  const int node = blockIdx.x * 8 + (threadIdx.x >> 5);
  const int sub = threadIdx.x & 31;
  const int c0 = sub * 4;
  const size_t qbase = (size_t)node * DD + c0;

  u16x4 qr = *(const u16x4*)(q + qbase);
  const float qv0 = b2f(qr[0]), qv1 = b2f(qr[1]), qv2 = b2f(qr[2]), qv3 = b2f(qr[3]);

  int sv[KNN];
  const int* sp = src + (size_t)node * KNN;
#pragma unroll
  for (int j = 0; j < KNN; j++) sv[j] = sp[j];

  float a0 = 0.f, a1 = 0.f, a2 = 0.f, a3 = 0.f, z = 0.f;
  const float inv_sqrt_hd = 0.17677669529663687f;  // 1/sqrt(32)
#pragma unroll 10
  for (int j = 0; j < KNN; j++) {
    u16x8 kvr = *(const u16x8*)(kv + (size_t)sv[j] * 256 + c0 * 2);
    float p = b2f(kvr[0]) * qv0 + b2f(kvr[2]) * qv1 + b2f(kvr[4]) * qv2 + b2f(kvr[6]) * qv3;
    p += __shfl_xor(p, 1);
    p += __shfl_xor(p, 2);
    p += __shfl_xor(p, 4);
    float sc = __expf(fminf(fmaxf(p * inv_sqrt_hd, -5.f), 5.f));
    z += sc;
    a0 += sc * b2f(kvr[1]);
    a1 += sc * b2f(kvr[3]);
    a2 += sc * b2f(kvr[5]);
    a3 += sc * b2f(kvr[7]);
  }
  float inv = 1.f / (z + 1e-6f);
  u16x4 o;
  o[0] = f2b(a0 * inv); o[1] = f2b(a1 * inv);
  o[2] = f2b(a2 * inv); o[3] = f2b(a3 * inv);
  *(u16x4*)(attnb + qbase) = o;
}

// ---------------- fused kernel B: out = node + silu(bn2(node)@W1)@W2,
//                  node = attn@Wo + bo + f  (kept in registers) ----------------
// 5 weight phases (Wo, W1a, W2a, W1b, W2b), each staged per-BLOCK into LDS once
// (4x cut in L2 weight stream). Wave-private tile T for C/D->B-frag relayout
// unchanged (no barriers needed for it).
__global__ __launch_bounds__(256) void womlp_kernel(
    const u16* __restrict__ attnb, const float* __restrict__ f, const u16* __restrict__ WTf,
    const float* __restrict__ bof, const float* __restrict__ sc2, const float* __restrict__ bb2,
    float* __restrict__ out)
{
  __shared__ u16 LW[16384];  // 32 KB staged weight matrix
  __shared__ u16 T[8704];    // 4 waves x 2176 u16 (16 rows x 136)
  const int tid = threadIdx.x;
  const int wave = tid >> 6, lane = tid & 63, quad = lane >> 4, l16 = lane & 15;
  const int rowbase = blockIdx.x * 64 + wave * 16;
  u16* tile = T + wave * 2176;
  int arow = rowbase + l16;
  if (arow >= NN) arow = NN - 1;

  // ---- phase Wo ----
  bf16x8 af[4];
  const u16* ap = attnb + (size_t)arow * DD + quad * 8;
#pragma unroll
  for (int ks = 0; ks < 4; ks++) af[ks] = *(const bf16x8*)(ap + ks * 32);

  stage_lds(LW, WTf + 49152, tid);
  __syncthreads();

  f32x4 nv[8];
#pragma unroll
  for (int ct = 0; ct < 8; ct++) nv[ct] = (f32x4){0.f, 0.f, 0.f, 0.f};
#pragma unroll
  for (int ct = 0; ct < 8; ct++)
#pragma unroll
    for (int ks = 0; ks < 4; ks++) {
      bf16x8 wf = *(const bf16x8*)(LW + ((ct * 4 + ks) * 64 + lane) * 8);
      nv[ct] = __builtin_amdgcn_mfma_f32_16x16x32_bf16(wf, af[ks], nv[ct], 0, 0, 0);
    }

  // node = nv + bo + f (registers); h2 = bn2(node) -> tile -> B-frags
#pragma unroll
  for (int ct = 0; ct < 8; ct++) {
    int ch0 = ct * 16 + quad * 4;
    f32x4 bo4 = *(const f32x4*)(bof + ch0);
    f32x4 s4  = *(const f32x4*)(sc2 + ch0);
    f32x4 b4  = *(const f32x4*)(bb2 + ch0);
    f32x4 f4  = *(const f32x4*)(f + (size_t)arow * DD + ch0);
    nv[ct] = nv[ct] + bo4 + f4;
    u16x4 h4;
#pragma unroll
    for (int r = 0; r < 4; r++) h4[r] = f2b(nv[ct][r] * s4[r] + b4[r]);
    *(u16x4*)(tile + l16 * 136 + ch0) = h4;
  }
  bf16x8 hf[4];
#pragma unroll
  for (int ksl = 0; ksl < 4; ksl++)
    hf[ksl] = *(const bf16x8*)(tile + l16 * 136 + ksl * 32 + quad * 8);

  f32x4 acc3[8];
#pragma unroll
  for (int ct = 0; ct < 8; ct++) acc3[ct] = (f32x4){0.f, 0.f, 0.f, 0.f};

  // ---- MLP m-loop: phases {W1m, W2m} x m=0,1 ----
#pragma unroll
  for (int m = 0; m < 2; m++) {
    __syncthreads();                                // previous LW readers done
    stage_lds(LW, WTf + 65536 + m * 16384, tid);    // W1 half m
    __syncthreads();

    f32x4 acc2[8];
#pragma unroll
    for (int ct = 0; ct < 8; ct++) acc2[ct] = (f32x4){0.f, 0.f, 0.f, 0.f};
#pragma unroll
    for (int ct = 0; ct < 8; ct++)
#pragma unroll
      for (int ks = 0; ks < 4; ks++) {
        bf16x8 wf = *(const bf16x8*)(LW + ((ct * 4 + ks) * 64 + lane) * 8);
        acc2[ct] = __builtin_amdgcn_mfma_f32_16x16x32_bf16(wf, hf[ks], acc2[ct], 0, 0, 0);
      }
    // silu -> tile (C/D layout) -> read back as B-frags
#pragma unroll
    for (int ct = 0; ct < 8; ct++) {
      int ch0 = ct * 16 + quad * 4;
      u16x4 i4;
#pragma unroll
      for (int r = 0; r < 4; r++) {
        float x = acc2[ct][r];
        i4[r] = f2b(x / (1.f + __expf(-x)));
      }
      *(u16x4*)(tile + l16 * 136 + ch0) = i4;
    }
    bf16x8 iff[4];
#pragma unroll
    for (int ksl = 0; ksl < 4; ksl++)
      iff[ksl] = *(const bf16x8*)(tile + l16 * 136 + ksl * 32 + quad * 8);

    __syncthreads();                                // W1m readers done
    stage_lds(LW, WTf + 98304 + m * 16384, tid);    // W2 k-half m (frags m*32..m*32+31)
    __syncthreads();
#pragma unroll
    for (int ct = 0; ct < 8; ct++)
#pragma unroll
      for (int ksl = 0; ksl < 4; ksl++) {
        bf16x8 wf = *(const bf16x8*)(LW + ((ct * 4 + ksl) * 64 + lane) * 8);
        acc3[ct] = __builtin_amdgcn_mfma_f32_16x16x32_bf16(wf, iff[ksl], acc3[ct], 0, 0, 0);
      }
  }

  // ---- out = node + mlp ----
  const int srow = rowbase + l16;
  if (srow < NN) {
#pragma unroll
    for (int ct = 0; ct < 8; ct++) {
      int ch0 = ct * 16 + quad * 4;
      *(f32x4*)(out + (size_t)srow * DD + ch0) = acc3[ct] + nv[ct];
    }
  }
}

extern "C" void kernel_launch(void* const* d_in, const int* in_sizes, int n_in,
                              void* d_out, int out_size, void* d_ws, size_t ws_size,
                              hipStream_t stream) {
  const float* f  = (const float*)d_in[0];
  const int* src  = (const int*)d_in[1];
  // d_in[2] = dst (structure known: repeat(arange(N),20)) -- unused
  const float* g1 = (const float*)d_in[3];
  const float* b1 = (const float*)d_in[4];
  const float* m1 = (const float*)d_in[5];
  const float* v1 = (const float*)d_in[6];
  const float* Wq = (const float*)d_in[7];
  const float* Wk = (const float*)d_in[8];
  const float* Wv = (const float*)d_in[9];
  const float* Wo = (const float*)d_in[10];
  const float* bo = (const float*)d_in[11];
  const float* g2 = (const float*)d_in[12];
  const float* b2 = (const float*)d_in[13];
  const float* m2 = (const float*)d_in[14];
  const float* v2 = (const float*)d_in[15];
  const float* W1 = (const float*)d_in[16];
  const float* W2 = (const float*)d_in[17];
  float* out = (float*)d_out;   // f32 output

  char* ws = (char*)d_ws;
  u16*  WTf = (u16*)(ws + 0);                    // 262144 B
  float* sc1 = (float*)(ws + 262144);
  float* bb1 = (float*)(ws + 262656);
  float* sc2 = (float*)(ws + 263168);
  float* bb2 = (float*)(ws + 263680);
  float* bof = (float*)(ws + 264192);
  u16*   qb    = (u16*)(ws + (1u << 20));
  u16*   kvb   = (u16*)(ws + 27262976u);
  u16*   attnb = (u16*)(ws + 80740352u);

  stage_weights_kernel<<<65, 256, 0, stream>>>(
      Wq, Wk, Wv, Wo, W1, W2, g1, b1, m1, v1, g2, b2, m2, v2, bo,
      WTf, sc1, bb1, sc2, bb2, bof);

  const int ggrid = (NN + 63) / 64;  // 1563
  qkv_kernel<<<ggrid, 256, 0, stream>>>(f, WTf, sc1, bb1, qb, kvb);
  attn_kernel<<<NN / 8, 256, 0, stream>>>(qb, kvb, src, attnb);
  womlp_kernel<<<ggrid, 256, 0, stream>>>(attnb, f, WTf, bof, sc2, bb2, out);
}

// Round 3
// 348.638 us; speedup vs baseline: 1.3367x; 1.0938x over previous
//
#include <hip/hip_runtime.h>
#include <hip/hip_bf16.h>

#define NN 100000
#define DD 128
#define KNN 20

typedef unsigned short u16;
typedef __attribute__((ext_vector_type(8))) __bf16 bf16x8;
typedef __attribute__((ext_vector_type(4))) float f32x4;
typedef __attribute__((ext_vector_type(4))) unsigned short u16x4;
typedef __attribute__((ext_vector_type(8))) unsigned short u16x8;

__device__ __forceinline__ float b2f(u16 b) {
  unsigned int u = ((unsigned int)b) << 16;
  float f;
  __builtin_memcpy(&f, &u, 4);
  return f;
}
__device__ __forceinline__ u16 f2b(float f) {
  unsigned int u;
  __builtin_memcpy(&u, &f, 4);
  u += 0x7fffu + ((u >> 16) & 1u);
  return (u16)(u >> 16);
}

// ---------------- weight staging: f32 W -> bf16 frag-linear W^T blocks ----------------
// Frag idx = kc*32 + ct*4 + ksl (ks = kc*4+ksl); dst[(idx*64+lane)*8 + j]
//   = bf16( W[(ks*32 + quad*8 + j)*wstride + colbase + ct*16 + l16] )
// Used as MFMA *A*-operand: A[m=l16 -> wcol][k=quad*8+j].
__device__ __forceinline__ void stage_frag(const float* __restrict__ W, int wstride,
                                           int colbase, u16* __restrict__ dst, int f) {
  int lane = f & 63;
  int t2 = f >> 6;
  int ksl = t2 & 3;
  int ct = (t2 >> 2) & 7;
  int kc = t2 >> 5;
  int ks = kc * 4 + ksl;
  int quad = lane >> 4, l16 = lane & 15;
  const float* src = W + (size_t)(ks * 32 + quad * 8) * wstride + colbase + ct * 16 + l16;
  u16x8 o;
#pragma unroll
  for (int j = 0; j < 8; j++) o[j] = f2b(src[(size_t)j * wstride]);
  *(u16x8*)(dst + (size_t)f * 8) = o;
}

// WTf (u16 offsets): Wq@0, Wk@16384, Wv@32768, Wo@49152, W1a@65536, W1b@81920, W2@98304
__global__ __launch_bounds__(256) void stage_weights_kernel(
    const float* __restrict__ Wq, const float* __restrict__ Wk, const float* __restrict__ Wv,
    const float* __restrict__ Wo, const float* __restrict__ W1, const float* __restrict__ W2,
    const float* __restrict__ g1, const float* __restrict__ b1,
    const float* __restrict__ m1, const float* __restrict__ v1,
    const float* __restrict__ g2, const float* __restrict__ b2,
    const float* __restrict__ m2, const float* __restrict__ v2,
    const float* __restrict__ bo,
    u16* __restrict__ WTf,
    float* __restrict__ sc1, float* __restrict__ bb1,
    float* __restrict__ sc2, float* __restrict__ bb2, float* __restrict__ bof)
{
  int t = blockIdx.x * 256 + threadIdx.x;
  if (t < 2048)       stage_frag(Wq, 128, 0,   WTf + 0,     t);
  else if (t < 4096)  stage_frag(Wk, 128, 0,   WTf + 16384, t - 2048);
  else if (t < 6144)  stage_frag(Wv, 128, 0,   WTf + 32768, t - 4096);
  else if (t < 8192)  stage_frag(Wo, 128, 0,   WTf + 49152, t - 6144);
  else if (t < 10240) stage_frag(W1, 256, 0,   WTf + 65536, t - 8192);
  else if (t < 12288) stage_frag(W1, 256, 128, WTf + 81920, t - 10240);
  else if (t < 16384) stage_frag(W2, 128, 0,   WTf + 98304, t - 12288);
  else if (t < 16512) {
    int c = t - 16384;
    float s1 = g1[c] * rsqrtf(v1[c] + 1e-5f);
    sc1[c] = s1; bb1[c] = b1[c] - m1[c] * s1;
    float s2 = g2[c] * rsqrtf(v2[c] + 1e-5f);
    sc2[c] = s2; bb2[c] = b2[c] - m2[c] * s2;
    bof[c] = bo[c];
  }
}

// ---- T14 weight staging helpers: reg-prefetch (issue early) / LDS-write (late) ----
#define LOADW(off)                                                            \
  do {                                                                        \
    _Pragma("unroll") for (int k2 = 0; k2 < 8; k2++)                          \
        pw[k2] = *(const u16x8*)(WTf + (off) + (size_t)(k2 * 256 + tid) * 8); \
  } while (0)
#define WRITEW()                                                              \
  do {                                                                        \
    _Pragma("unroll") for (int k2 = 0; k2 < 8; k2++)                          \
        *(u16x8*)(LW + (size_t)(k2 * 256 + tid) * 8) = pw[k2];                \
  } while (0)

// ---------------- kernel A: fused bn1 + QKV, 16 rows/wave ----------------
// Weights staged per-block into LDS; T14 split: next phase's global loads are
// issued BEFORE the current MFMA loop (latency hides under compute), ds_write
// lands after the readers-done barrier.
__global__ __launch_bounds__(256) void qkv_kernel(
    const float* __restrict__ f, const u16* __restrict__ WTf,
    const float* __restrict__ sc1, const float* __restrict__ bb1,
    u16* __restrict__ qb, u16* __restrict__ kvb)
{
  __shared__ u16 LW[16384];  // 32 KB: one staged weight matrix
  const int tid = threadIdx.x;
  const int wave = tid >> 6, lane = tid & 63, quad = lane >> 4, l16 = lane & 15;
  const int rowbase = blockIdx.x * 64 + wave * 16;
  int arow = rowbase + l16;
  if (arow >= NN) arow = NN - 1;

  // act frags (B-op): lane = row l16, k = ks*32+quad*8+j ; bn1 folded in regs
  bf16x8 af[4];
#pragma unroll
  for (int ks = 0; ks < 4; ks++) {
    int ch = ks * 32 + quad * 8;
    f32x4 s0 = *(const f32x4*)(sc1 + ch), s1 = *(const f32x4*)(sc1 + ch + 4);
    f32x4 c0 = *(const f32x4*)(bb1 + ch), c1 = *(const f32x4*)(bb1 + ch + 4);
    const float* fp = f + (size_t)arow * DD + ch;
    f32x4 x0 = *(const f32x4*)(fp), x1 = *(const f32x4*)(fp + 4);
    u16x8 hv;
#pragma unroll
    for (int j = 0; j < 4; j++) {
      hv[j]     = f2b(x0[j] * s0[j] + c0[j]);
      hv[j + 4] = f2b(x1[j] * s1[j] + c1[j]);
    }
    af[ks] = __builtin_bit_cast(bf16x8, hv);
  }

  u16x8 pw[8];
  LOADW(0);        // Wq
  WRITEW();
  __syncthreads();

  const int srow = rowbase + l16;
  u16x4 ks16[8];  // k results held for interleaved kv store
#pragma unroll
  for (int m = 0; m < 3; m++) {
    if (m < 2) LOADW((m + 1) * 16384);   // prefetch next weights under MFMA
    f32x4 acc[8];
#pragma unroll
    for (int ct = 0; ct < 8; ct++) acc[ct] = (f32x4){0.f, 0.f, 0.f, 0.f};
#pragma unroll
    for (int ct = 0; ct < 8; ct++)
#pragma unroll
      for (int ks = 0; ks < 4; ks++) {
        bf16x8 wf = *(const bf16x8*)(LW + ((ct * 4 + ks) * 64 + lane) * 8);
        acc[ct] = __builtin_amdgcn_mfma_f32_16x16x32_bf16(wf, af[ks], acc[ct], 0, 0, 0);
      }
    __syncthreads();                     // all waves done reading LW
    if (m < 2) WRITEW();                 // stage next phase (loads already landed)
#pragma unroll
    for (int ct = 0; ct < 8; ct++) {
      int ch0 = ct * 16 + quad * 4;
      if (m == 0) {
        if (srow < NN) {
          u16x4 o;
#pragma unroll
          for (int r = 0; r < 4; r++) o[r] = f2b(acc[ct][r]);
          *(u16x4*)(qb + (size_t)srow * DD + ch0) = o;
        }
      } else if (m == 1) {
        u16x4 o;
#pragma unroll
        for (int r = 0; r < 4; r++) o[r] = f2b(acc[ct][r]);
        ks16[ct] = o;
      } else {
        if (srow < NN) {
          u16x8 o;
#pragma unroll
          for (int r = 0; r < 4; r++) {
            o[2 * r] = ks16[ct][r];
            o[2 * r + 1] = f2b(acc[ct][r]);
          }
          *(u16x8*)(kvb + (size_t)srow * 256 + ch0 * 2) = o;
        }
      }
    }
    if (m < 2) __syncthreads();          // LW writes visible before next phase
  }
}

// ---------------- attention: 32 lanes/node, 4 ch/lane, interleaved kv ----------------
// MLP fix: all 20 kv-row gathers issued before any consumption. VGPR 24 -> ~120;
// per-wave outstanding loads 2 -> 20 (net ~6x more MLP per CU despite occupancy drop).
__global__ __launch_bounds__(256) void attn_kernel(
    const u16* __restrict__ q, const u16* __restrict__ kv,
    const int* __restrict__ src, u16* __restrict__ attnb)
{
  const int node = blockIdx.x * 8 + (threadIdx.x >> 5);
  const int sub = threadIdx.x & 31;
  const int c0 = sub * 4;
  const size_t qbase = (size_t)node * DD + c0;

  u16x4 qr = *(const u16x4*)(q + qbase);
  const float qv0 = b2f(qr[0]), qv1 = b2f(qr[1]), qv2 = b2f(qr[2]), qv3 = b2f(qr[3]);

  const int* sp = src + (size_t)node * KNN;
  int sv[KNN];
#pragma unroll
  for (int j = 0; j < KNN; j++) sv[j] = sp[j];

  // issue ALL gathers up front (independent; compiler stages vmcnt waits on use)
  u16x8 kvr[KNN];
#pragma unroll
  for (int j = 0; j < KNN; j++)
    kvr[j] = *(const u16x8*)(kv + (size_t)sv[j] * 256 + c0 * 2);

  float a0 = 0.f, a1 = 0.f, a2 = 0.f, a3 = 0.f, z = 0.f;
  const float inv_sqrt_hd = 0.17677669529663687f;  // 1/sqrt(32)
#pragma unroll
  for (int j = 0; j < KNN; j++) {
    float p = b2f(kvr[j][0]) * qv0 + b2f(kvr[j][2]) * qv1 +
              b2f(kvr[j][4]) * qv2 + b2f(kvr[j][6]) * qv3;
    p += __shfl_xor(p, 1);
    p += __shfl_xor(p, 2);
    p += __shfl_xor(p, 4);
    float sc = __expf(fminf(fmaxf(p * inv_sqrt_hd, -5.f), 5.f));
    z += sc;
    a0 += sc * b2f(kvr[j][1]);
    a1 += sc * b2f(kvr[j][3]);
    a2 += sc * b2f(kvr[j][5]);
    a3 += sc * b2f(kvr[j][7]);
  }
  float inv = 1.f / (z + 1e-6f);
  u16x4 o;
  o[0] = f2b(a0 * inv); o[1] = f2b(a1 * inv);
  o[2] = f2b(a2 * inv); o[3] = f2b(a3 * inv);
  *(u16x4*)(attnb + qbase) = o;
}

// ---------------- fused kernel B: out = node + silu(bn2(node)@W1)@W2,
//                  node = attn@Wo + bo + f  (kept in registers) ----------------
// 5 weight phases [Wo, W1a, W2a, W1b, W2b]; T14 prefetch chain: each phase's
// MFMA loop hides the next phase's global weight loads.
__global__ __launch_bounds__(256) void womlp_kernel(
    const u16* __restrict__ attnb, const float* __restrict__ f, const u16* __restrict__ WTf,
    const float* __restrict__ bof, const float* __restrict__ sc2, const float* __restrict__ bb2,
    float* __restrict__ out)
{
  __shared__ u16 LW[16384];  // 32 KB staged weight matrix
  __shared__ u16 T[8704];    // 4 waves x 2176 u16 (16 rows x 136)
  const int tid = threadIdx.x;
  const int wave = tid >> 6, lane = tid & 63, quad = lane >> 4, l16 = lane & 15;
  const int rowbase = blockIdx.x * 64 + wave * 16;
  u16* tile = T + wave * 2176;
  int arow = rowbase + l16;
  if (arow >= NN) arow = NN - 1;

  // ---- prologue: stage Wo ----
  bf16x8 af[4];
  const u16* ap = attnb + (size_t)arow * DD + quad * 8;
#pragma unroll
  for (int ks = 0; ks < 4; ks++) af[ks] = *(const bf16x8*)(ap + ks * 32);

  u16x8 pw[8];
  LOADW(49152);   // Wo
  WRITEW();
  __syncthreads();

  // ---- phase Wo ----
  LOADW(65536);   // prefetch W1a under the Wo MFMAs
  f32x4 nv[8];
#pragma unroll
  for (int ct = 0; ct < 8; ct++) nv[ct] = (f32x4){0.f, 0.f, 0.f, 0.f};
#pragma unroll
  for (int ct = 0; ct < 8; ct++)
#pragma unroll
    for (int ks = 0; ks < 4; ks++) {
      bf16x8 wf = *(const bf16x8*)(LW + ((ct * 4 + ks) * 64 + lane) * 8);
      nv[ct] = __builtin_amdgcn_mfma_f32_16x16x32_bf16(wf, af[ks], nv[ct], 0, 0, 0);
    }

  // node = nv + bo + f (registers); h2 = bn2(node) -> tile -> B-frags
#pragma unroll
  for (int ct = 0; ct < 8; ct++) {
    int ch0 = ct * 16 + quad * 4;
    f32x4 bo4 = *(const f32x4*)(bof + ch0);
    f32x4 s4  = *(const f32x4*)(sc2 + ch0);
    f32x4 b4  = *(const f32x4*)(bb2 + ch0);
    f32x4 f4  = *(const f32x4*)(f + (size_t)arow * DD + ch0);
    nv[ct] = nv[ct] + bo4 + f4;
    u16x4 h4;
#pragma unroll
    for (int r = 0; r < 4; r++) h4[r] = f2b(nv[ct][r] * s4[r] + b4[r]);
    *(u16x4*)(tile + l16 * 136 + ch0) = h4;
  }
  bf16x8 hf[4];
#pragma unroll
  for (int ksl = 0; ksl < 4; ksl++)
    hf[ksl] = *(const bf16x8*)(tile + l16 * 136 + ksl * 32 + quad * 8);

  __syncthreads();   // Wo readers done
  WRITEW();          // W1a
  __syncthreads();

  f32x4 acc3[8];
#pragma unroll
  for (int ct = 0; ct < 8; ct++) acc3[ct] = (f32x4){0.f, 0.f, 0.f, 0.f};

  // ---- MLP m-loop: phases {W1m, W2m} x m=0,1 ----
#pragma unroll
  for (int m = 0; m < 2; m++) {
    // --- phase W1m (already in LW) ---
    LOADW(98304 + m * 16384);   // prefetch W2m
    f32x4 acc2[8];
#pragma unroll
    for (int ct = 0; ct < 8; ct++) acc2[ct] = (f32x4){0.f, 0.f, 0.f, 0.f};
#pragma unroll
    for (int ct = 0; ct < 8; ct++)
#pragma unroll
      for (int ks = 0; ks < 4; ks++) {
        bf16x8 wf = *(const bf16x8*)(LW + ((ct * 4 + ks) * 64 + lane) * 8);
        acc2[ct] = __builtin_amdgcn_mfma_f32_16x16x32_bf16(wf, hf[ks], acc2[ct], 0, 0, 0);
      }
    // silu -> tile (C/D layout) -> read back as B-frags
#pragma unroll
    for (int ct = 0; ct < 8; ct++) {
      int ch0 = ct * 16 + quad * 4;
      u16x4 i4;
#pragma unroll
      for (int r = 0; r < 4; r++) {
        float x = acc2[ct][r];
        i4[r] = f2b(x / (1.f + __expf(-x)));
      }
      *(u16x4*)(tile + l16 * 136 + ch0) = i4;
    }
    bf16x8 iff[4];
#pragma unroll
    for (int ksl = 0; ksl < 4; ksl++)
      iff[ksl] = *(const bf16x8*)(tile + l16 * 136 + ksl * 32 + quad * 8);

    __syncthreads();   // W1m readers done
    WRITEW();          // W2m
    __syncthreads();

    // --- phase W2m ---
    if (m == 0) LOADW(81920);   // prefetch W1b under the W2a MFMAs
#pragma unroll
    for (int ct = 0; ct < 8; ct++)
#pragma unroll
      for (int ksl = 0; ksl < 4; ksl++) {
        bf16x8 wf = *(const bf16x8*)(LW + ((ct * 4 + ksl) * 64 + lane) * 8);
        acc3[ct] = __builtin_amdgcn_mfma_f32_16x16x32_bf16(wf, iff[ksl], acc3[ct], 0, 0, 0);
      }
    if (m == 0) {
      __syncthreads();  // W2a readers done
      WRITEW();         // W1b
      __syncthreads();
    }
  }

  // ---- out = node + mlp ----
  const int srow = rowbase + l16;
  if (srow < NN) {
#pragma unroll
    for (int ct = 0; ct < 8; ct++) {
      int ch0 = ct * 16 + quad * 4;
      *(f32x4*)(out + (size_t)srow * DD + ch0) = acc3[ct] + nv[ct];
    }
  }
}

extern "C" void kernel_launch(void* const* d_in, const int* in_sizes, int n_in,
                              void* d_out, int out_size, void* d_ws, size_t ws_size,
                              hipStream_t stream) {
  const float* f  = (const float*)d_in[0];
  const int* src  = (const int*)d_in[1];
  // d_in[2] = dst (structure known: repeat(arange(N),20)) -- unused
  const float* g1 = (const float*)d_in[3];
  const float* b1 = (const float*)d_in[4];
  const float* m1 = (const float*)d_in[5];
  const float* v1 = (const float*)d_in[6];
  const float* Wq = (const float*)d_in[7];
  const float* Wk = (const float*)d_in[8];
  const float* Wv = (const float*)d_in[9];
  const float* Wo = (const float*)d_in[10];
  const float* bo = (const float*)d_in[11];
  const float* g2 = (const float*)d_in[12];
  const float* b2 = (const float*)d_in[13];
  const float* m2 = (const float*)d_in[14];
  const float* v2 = (const float*)d_in[15];
  const float* W1 = (const float*)d_in[16];
  const float* W2 = (const float*)d_in[17];
  float* out = (float*)d_out;   // f32 output

  char* ws = (char*)d_ws;
  u16*  WTf = (u16*)(ws + 0);                    // 262144 B
  float* sc1 = (float*)(ws + 262144);
  float* bb1 = (float*)(ws + 262656);
  float* sc2 = (float*)(ws + 263168);
  float* bb2 = (float*)(ws + 263680);
  float* bof = (float*)(ws + 264192);
  u16*   qb    = (u16*)(ws + (1u << 20));
  u16*   kvb   = (u16*)(ws + 27262976u);
  u16*   attnb = (u16*)(ws + 80740352u);

  stage_weights_kernel<<<65, 256, 0, stream>>>(
      Wq, Wk, Wv, Wo, W1, W2, g1, b1, m1, v1, g2, b2, m2, v2, bo,
      WTf, sc1, bb1, sc2, bb2, bof);

  const int ggrid = (NN + 63) / 64;  // 1563
  qkv_kernel<<<ggrid, 256, 0, stream>>>(f, WTf, sc1, bb1, qb, kvb);
  attn_kernel<<<NN / 8, 256, 0, stream>>>(qb, kvb, src, attnb);
  womlp_kernel<<<ggrid, 256, 0, stream>>>(attnb, f, WTf, bof, sc2, bb2, out);
}